// Round 3
// baseline (251.159 us; speedup 1.0000x reference)
//
#include <hip/hip_runtime.h>
#include <hip/hip_bf16.h>

#define NB 4
#define NR 8
#define NS 8
#define NL 256
#define NH 768
#define NA 256
#define NTD 100

// ---- workspace layout (float offsets) ----
#define WX_F 0
#define WX_B (WX_F + NB*NL*NA)      // 262144
#define WR_F (WX_B + NB*NL*NA)      // 524288
#define WR_B (WR_F + NR*NA)         // 526336
#define WG_F (WR_B + NR*NA)         // 528384
#define WG_B (WG_F + NB*NA)         // 529408
#define C_F  (WG_B + NB*NA)         // 530432  (B,R,H)
#define C_B  (C_F + NB*NR*NH)       // 555008
#define QV   (C_B + NB*NR*NH)       // 579584  8 vectors of 768
#define SCAL (QV + 8*NH)            // 585728  8 scalars
#define DXL  (SCAL + 8)             // 585736  4 x (B*L)
#define XB   (DXL + 4*NB*NL)        // bf16 Xb[1024][768]
#define WT   (XB + (NB*NL*NH)/2)    // bf16 Wt[2][256][768]

// output offsets (floats)
#define O_FT_S 4096
#define O_FT_E 69632
#define O_BH_S 135168
#define O_BH_E 200704

typedef __attribute__((ext_vector_type(8))) short short8;
typedef __attribute__((ext_vector_type(4))) float f32x4;

struct bh4 { __hip_bfloat16 a, b, c, d; };

__device__ __forceinline__ float tanh_fast(float x) {
    x = fminf(15.f, fmaxf(-15.f, x));
    float t = __expf(2.f * x);
    return (t - 1.f) / (t + 1.f);
}

__device__ __forceinline__ float wave_reduce(float v) {
    #pragma unroll
    for (int off = 32; off > 0; off >>= 1) v += __shfl_down(v, off);
    return v;
}

// ================= K1: setup — X/W bf16 convert + all small precomputes =================
// bid 0..383   : X f32->bf16 (2048 elems/block)
// bid 384..575 : W transpose+cvt (2 32x32 tiles/block)
// bid 576..599 : vec@mat (wr/wg rows)
// bid 600..607 : scalar dots
// bid 608..991 : 768x768 matvec pairs (q/u vectors)
__global__ void __launch_bounds__(512) k_setup(const float* __restrict__ X,
                      const float* __restrict__ fra_Wx, const float* __restrict__ bra_Wx,
                      const float* __restrict__ sem, const float* __restrict__ transe,
                      const float* __restrict__ X_mean,
                      const float* __restrict__ fra_Wr, const float* __restrict__ fra_br,
                      const float* __restrict__ fra_Wg, const float* __restrict__ fra_bg,
                      const float* __restrict__ bra_Wr, const float* __restrict__ bra_br,
                      const float* __restrict__ bra_Wg, const float* __restrict__ bra_bg,
                      const float* __restrict__ ffe_Ws, const float* __restrict__ ffe_bs,
                      const float* __restrict__ ffe_Wx, const float* __restrict__ ffe_bx,
                      const float* __restrict__ bfe_Ws, const float* __restrict__ bfe_bs,
                      const float* __restrict__ bfe_Wx, const float* __restrict__ bfe_bx,
                      const float* __restrict__ ft_ws, const float* __restrict__ ft_we,
                      const float* __restrict__ bh_ws, const float* __restrict__ bh_we,
                      float* __restrict__ ws) {
    __shared__ float smem[2112];
    const int bid = blockIdx.x, tid = threadIdx.x;

    if (bid < 384) {
        __hip_bfloat16* xb = (__hip_bfloat16*)(ws + XB);
        const int i0 = bid*2048 + tid*4;
        const float4 v = *(const float4*)(X + i0);
        bh4 o = { __float2bfloat16(v.x), __float2bfloat16(v.y),
                  __float2bfloat16(v.z), __float2bfloat16(v.w) };
        *(bh4*)(xb + i0) = o;
    } else if (bid < 576) {
        __hip_bfloat16* wt = (__hip_bfloat16*)(ws + WT);
        const int t2 = bid - 384;               // 0..191
        const int mt = t2 / 96;                 // 0 fwd, 1 bwd
        const int half = tid >> 8, tid2 = tid & 255;
        const int tile = (t2 % 96)*2 + half;    // 0..191
        const int h0 = (tile >> 3) * 32, c0 = (tile & 7) * 32;
        const float* W = mt ? bra_Wx : fra_Wx;
        float (*sh)[33] = (float(*)[33])(smem + half*1056);
        const int r = tid2 >> 5, c = tid2 & 31;
        #pragma unroll
        for (int i = 0; i < 4; ++i)
            sh[r + 8*i][c] = W[(size_t)(h0 + r + 8*i)*NA + c0 + c];
        __syncthreads();
        const int cw = tid2 >> 5, hw = tid2 & 31;
        #pragma unroll
        for (int i = 0; i < 4; ++i)
            wt[(size_t)(mt*NA + c0 + cw + 8*i)*NH + h0 + hw] = __float2bfloat16(sh[hw][cw + 8*i]);
    } else if (bid < 600) {
        float* sh = smem;            // 768
        float* red2 = smem + 768;    // 512
        const int q = bid - 576;
        const float* s; const float* W; const float* bias; float* out; int K;
        if (q < 8)       { s = sem + q*NH;         W = fra_Wr; bias = fra_br; out = ws + WR_F + q*NA;      K = NH;  }
        else if (q < 16) { s = transe + (q-8)*NTD; W = bra_Wr; bias = bra_br; out = ws + WR_B + (q-8)*NA;  K = NTD; }
        else if (q < 20) { s = X_mean + (q-16)*NH; W = fra_Wg; bias = fra_bg; out = ws + WG_F + (q-16)*NA; K = NH;  }
        else             { s = X_mean + (q-20)*NH; W = bra_Wg; bias = bra_bg; out = ws + WG_B + (q-20)*NA; K = NH;  }
        for (int j = tid; j < K; j += 512) sh[j] = s[j];
        __syncthreads();
        const int half = tid >> 8, col = tid & 255;
        const int khalf = (K/2) & ~15;
        const int k0 = half ? khalf : 0, k1 = half ? K : khalf;
        const float* Wc = W + col;
        float acc = 0.f;
        int k = k0;
        for (; k + 16 <= k1; k += 16) {
            float wb[16];
            #pragma unroll
            for (int i = 0; i < 16; ++i) wb[i] = Wc[(size_t)(k+i)*NA];
            #pragma unroll
            for (int i = 0; i < 16; ++i) acc += sh[k+i] * wb[i];
        }
        for (; k < k1; ++k) acc += sh[k] * Wc[(size_t)k*NA];
        red2[half*256 + col] = acc;
        __syncthreads();
        if (half == 0) out[col] = red2[col] + red2[256 + col] + bias[col];
    } else if (bid < 608) {
        float* red2 = smem;
        const int q = bid - 600;
        const float* a; const float* b2;
        switch (q) {
            case 0: a = ffe_bs; b2 = ft_ws; break;
            case 1: a = ffe_bs; b2 = ft_we; break;
            case 2: a = ffe_bx; b2 = ft_ws; break;
            case 3: a = ffe_bx; b2 = ft_we; break;
            case 4: a = bfe_bs; b2 = bh_ws; break;
            case 5: a = bfe_bs; b2 = bh_we; break;
            case 6: a = bfe_bx; b2 = bh_ws; break;
            default: a = bfe_bx; b2 = bh_we; break;
        }
        float p = a[tid]*b2[tid];
        if (tid < 256) p += a[tid+512]*b2[tid+512];
        red2[tid] = p; __syncthreads();
        for (int s2 = 256; s2 > 0; s2 >>= 1) { if (tid < s2) red2[tid] += red2[tid + s2]; __syncthreads(); }
        if (tid == 0) ws[SCAL + q] = red2[0];
    } else {
        const int idx = bid - 608;              // 0..383
        const int mi = idx / 96;
        const int row = (idx % 96)*8 + (tid >> 6);
        const int lane = tid & 63;
        const float* M; const float* v0; const float* v1; bool self;
        switch (mi) {
            case 0: M = ffe_Ws; v0 = ft_ws; v1 = ft_we; self = false; break;
            case 1: M = bfe_Ws; v0 = bh_ws; v1 = bh_we; self = false; break;
            case 2: M = ffe_Wx; v0 = ft_ws; v1 = ft_we; self = true;  break;
            default: M = bfe_Wx; v0 = bh_ws; v1 = bh_we; self = true; break;
        }
        const float4* mr4 = (const float4*)(M + (size_t)row*NH);
        const float4* va4 = (const float4*)v0;
        const float4* vb4 = (const float4*)v1;
        float a0 = 0.f, a1 = 0.f;
        #pragma unroll
        for (int i = 0; i < 3; ++i) {
            const float4 m4 = mr4[lane + 64*i];
            const float4 x4 = va4[lane + 64*i];
            const float4 y4 = vb4[lane + 64*i];
            a0 += m4.x*x4.x + m4.y*x4.y + m4.z*x4.z + m4.w*x4.w;
            a1 += m4.x*y4.x + m4.y*y4.y + m4.z*y4.z + m4.w*y4.w;
        }
        a0 = wave_reduce(a0); a1 = wave_reduce(a1);
        if (lane == 0) {
            ws[QV + (mi*2 + 0)*NH + row] = a0 + (self ? v0[row] : 0.f);
            ws[QV + (mi*2 + 1)*NH + row] = a1 + (self ? v1[row] : 0.f);
        }
    }
}

// ================= K2: bf16 MFMA GEMM  wx = X @ W + b =================
__global__ void __launch_bounds__(256) k_wx(const float* __restrict__ fra_bx,
                                            const float* __restrict__ bra_bx,
                                            float* __restrict__ ws) {
    const __hip_bfloat16* xb = (const __hip_bfloat16*)(ws + XB);
    const __hip_bfloat16* wt = (const __hip_bfloat16*)(ws + WT);
    const int bid = blockIdx.x, tid = threadIdx.x;
    const int fb = bid >> 8;
    const int rt = (bid & 255) >> 2, cg = bid & 3;
    const int wv = tid >> 6, lane = tid & 63;
    const int m0 = rt * 16, c0 = cg * 64 + wv * 16;
    const int r16 = lane & 15, koff = (lane >> 4) * 8;

    const short8* ap = (const short8*)(xb + (size_t)(m0 + r16)*NH + koff);
    const short8* bp = (const short8*)(wt + (size_t)(fb*NA + c0 + r16)*NH + koff);

    f32x4 acc = {0.f, 0.f, 0.f, 0.f};
    #pragma unroll
    for (int ks = 0; ks < 24; ks += 4) {
        short8 a0 = ap[(ks+0)*4], b0 = bp[(ks+0)*4];
        short8 a1 = ap[(ks+1)*4], b1 = bp[(ks+1)*4];
        short8 a2 = ap[(ks+2)*4], b2 = bp[(ks+2)*4];
        short8 a3 = ap[(ks+3)*4], b3 = bp[(ks+3)*4];
        acc = __builtin_amdgcn_mfma_f32_16x16x32_bf16(a0, b0, acc, 0, 0, 0);
        acc = __builtin_amdgcn_mfma_f32_16x16x32_bf16(a1, b1, acc, 0, 0, 0);
        acc = __builtin_amdgcn_mfma_f32_16x16x32_bf16(a2, b2, acc, 0, 0, 0);
        acc = __builtin_amdgcn_mfma_f32_16x16x32_bf16(a3, b3, acc, 0, 0, 0);
    }
    const float* bia = fb ? bra_bx : fra_bx;
    float* outp = ws + (fb ? WX_B : WX_F);
    const int col = c0 + r16;
    const float bb = bia[col];
    const int rbase = m0 + (lane >> 4) * 4;
    #pragma unroll
    for (int j = 0; j < 4; ++j)
        outp[(size_t)(rbase + j)*NA + col] = acc[j] + bb;
}

// ================= K3: attn (e->softmax->ctx, a in LDS) + dxl blocks =================
// bid 0..63   : attention for (fb,b,r) incl. context write to C
// bid 64..575 : dxl — 2 (b,l) rows/block, 4 dot-pairs each
__global__ void __launch_bounds__(512) k_attn_dxl(const float* __restrict__ X,
                       const float* __restrict__ fra_V, const float* __restrict__ fra_bv,
                       const float* __restrict__ bra_V, const float* __restrict__ bra_bv,
                       const float* __restrict__ fh_ws, const float* __restrict__ fh_bs,
                       const float* __restrict__ fh_we, const float* __restrict__ fh_be,
                       const float* __restrict__ bt_ws, const float* __restrict__ bt_bs,
                       const float* __restrict__ bt_we, const float* __restrict__ bt_be,
                       float* __restrict__ ws, float* __restrict__ out) {
    __shared__ float smem[1536];
    const int bid = blockIdx.x, tid = threadIdx.x;

    if (bid < 64) {
        float* wa_s = smem;          // 256
        float* v_s  = smem + 256;    // 256
        float* red  = smem + 512;    // 256
        float* part = smem + 768;    // 256
        float* a_s  = smem + 1024;   // 256
        const int fb = bid >> 5, b = (bid >> 3) & 3, r = bid & 7;
        const int l = tid & 255, half = tid >> 8;

        const float* wr = ws + (fb ? WR_B : WR_F) + r*NA;
        const float* wg = ws + (fb ? WG_B : WG_F) + b*NA;
        const float* V  = fb ? bra_V : fra_V;
        const float  bv = fb ? bra_bv[0] : fra_bv[0];
        const float* wxp = ws + (fb ? WX_B : WX_F);

        if (tid < 256) { wa_s[tid] = wr[tid] + wg[tid]; v_s[tid] = V[tid]; }
        __syncthreads();

        const float4* wxrow = (const float4*)(wxp + (size_t)(b*NL + l)*NA + half*128);
        float acc = 0.f;
        for (int a0 = 0; a0 < 32; a0 += 8) {
            float4 wb[8];
            #pragma unroll
            for (int i = 0; i < 8; ++i) wb[i] = wxrow[a0 + i];
            #pragma unroll
            for (int i = 0; i < 8; ++i) {
                const int a = half*128 + (a0 + i)*4;
                acc += tanh_fast(wb[i].x + wa_s[a+0]) * v_s[a+0];
                acc += tanh_fast(wb[i].y + wa_s[a+1]) * v_s[a+1];
                acc += tanh_fast(wb[i].z + wa_s[a+2]) * v_s[a+2];
                acc += tanh_fast(wb[i].w + wa_s[a+3]) * v_s[a+3];
            }
        }
        if (half) part[l] = acc;
        __syncthreads();

        float e = 0.f;
        if (!half) e = acc + part[l] + bv;
        if (tid < 256) red[tid] = e;
        __syncthreads();
        for (int s2 = 128; s2 > 0; s2 >>= 1) { if (tid < s2) red[tid] = fmaxf(red[tid], red[tid+s2]); __syncthreads(); }
        const float mx = red[0];
        __syncthreads();
        float p = 0.f;
        if (tid < 256) { p = __expf(e - mx); red[tid] = p; }
        __syncthreads();
        for (int s2 = 128; s2 > 0; s2 >>= 1) { if (tid < s2) red[tid] += red[tid+s2]; __syncthreads(); }
        if (tid < 256) a_s[tid] = p / red[0];
        __syncthreads();

        // context: c[h] = sum_l a[l] X[b,l,h]
        const float* Xb = X + (size_t)b*NL*NH;
        float* cc = ws + (fb ? C_B : C_F) + (size_t)(b*NR + r)*NH;
        for (int h = tid; h < NH; h += 512) {
            const float* Xp = Xb + h;
            float c = 0.f;
            for (int l0 = 0; l0 < NL; l0 += 8) {
                float xb_[8];
                #pragma unroll
                for (int i = 0; i < 8; ++i) xb_[i] = Xp[(size_t)(l0+i)*NH];
                #pragma unroll
                for (int i = 0; i < 8; ++i) c += a_s[l0+i] * xb_[i];
            }
            cc[h] = c;
        }
    } else {
        float* xr = smem;            // 2 x 768
        const int idx = bid - 64;    // 0..511
        const int m0 = idx * 2;
        const int g = tid >> 6, lane = tid & 63;
        const int row = g >> 2, w = g & 3;
        const int m = m0 + row;

        if (tid < 384) ((float4*)xr)[tid] = ((const float4*)(X + (size_t)m0*NH))[tid];
        __syncthreads();

        const float* v0; const float* v1; float add0, add1; float* o0; float* o1;
        if (w == 0)      { v0 = fh_ws; add0 = fh_bs[0]; o0 = out;        v1 = fh_we; add1 = fh_be[0]; o1 = out + 1024; }
        else if (w == 1) { v0 = bt_ws; add0 = bt_bs[0]; o0 = out + 2048; v1 = bt_we; add1 = bt_be[0]; o1 = out + 3072; }
        else if (w == 2) { v0 = ws + QV + 4*NH; add0 = ws[SCAL+2]; o0 = ws + DXL;
                           v1 = ws + QV + 5*NH; add1 = ws[SCAL+3]; o1 = ws + DXL + 1024; }
        else             { v0 = ws + QV + 6*NH; add0 = ws[SCAL+6]; o0 = ws + DXL + 2048;
                           v1 = ws + QV + 7*NH; add1 = ws[SCAL+7]; o1 = ws + DXL + 3072; }

        const float4* xr4 = (const float4*)(xr + row*NH);
        const float4* v04 = (const float4*)v0;
        const float4* v14 = (const float4*)v1;
        float a0 = 0.f, a1 = 0.f;
        #pragma unroll
        for (int i = 0; i < 3; ++i) {
            const float4 x4 = xr4[lane + 64*i];
            const float4 p4 = v04[lane + 64*i];
            const float4 q4 = v14[lane + 64*i];
            a0 += x4.x*p4.x + x4.y*p4.y + x4.z*p4.z + x4.w*p4.w;
            a1 += x4.x*q4.x + x4.y*q4.y + x4.z*q4.z + x4.w*q4.w;
        }
        a0 = wave_reduce(a0); a1 = wave_reduce(a1);
        if (lane == 0) { o0[m] = a0 + add0; o1[m] = a1 + add1; }
    }
}

// ================= K4: span gather + q-dots + per-block d3 + final output =================
__global__ void __launch_bounds__(256) k_skf(const float* __restrict__ X, const int* __restrict__ sk,
                     const float* __restrict__ sk_mask,
                     const float* __restrict__ ft_ws, const float* __restrict__ ft_bs,
                     const float* __restrict__ ft_we, const float* __restrict__ ft_be,
                     const float* __restrict__ bh_ws, const float* __restrict__ bh_bs,
                     const float* __restrict__ bh_we, const float* __restrict__ bh_be,
                     const float* __restrict__ ws, float* __restrict__ out) {
    __shared__ float avg[NH];
    __shared__ float d1_s[4], d3_s[4];
    const int brs = blockIdx.x;
    const int tid = threadIdx.x, w = tid >> 6, lane = tid & 63;
    const int b = brs >> 6, br = brs >> 3;
    const int i0 = sk[brs*2], i1 = sk[brs*2 + 1];
    const float mk = sk_mask[brs];

    if (tid < 192) {
        const float4 x0 = ((const float4*)(X + (size_t)(b*NL + i0)*NH))[tid];
        const float4 x1 = ((const float4*)(X + (size_t)(b*NL + i1)*NH))[tid];
        float4 o; o.x = 0.5f*(x0.x+x1.x); o.y = 0.5f*(x0.y+x1.y);
        o.z = 0.5f*(x0.z+x1.z); o.w = 0.5f*(x0.w+x1.w);
        ((float4*)avg)[tid] = o;
    }
    __syncthreads();

    // wave w: d1 (span dot with q_w) and d3 (c dot with head_w)
    const float4* q4 = (const float4*)(ws + QV + w*NH);
    const float4* av4 = (const float4*)avg;
    const float4* c4 = (const float4*)(ws + ((w < 2) ? C_F : C_B) + (size_t)br*NH);
    const float* v = (w == 0) ? ft_ws : (w == 1) ? ft_we : (w == 2) ? bh_ws : bh_we;
    const float4* vv4 = (const float4*)v;
    float acc = 0.f, d = 0.f;
    #pragma unroll
    for (int i = 0; i < 3; ++i) {
        const float4 a4 = av4[lane + 64*i];
        const float4 b4 = q4[lane + 64*i];
        const float4 e4 = c4[lane + 64*i];
        const float4 f4 = vv4[lane + 64*i];
        acc += a4.x*b4.x + a4.y*b4.y + a4.z*b4.z + a4.w*b4.w;
        d   += e4.x*f4.x + e4.y*f4.y + e4.z*f4.z + e4.w*f4.w;
    }
    acc = wave_reduce(acc); d = wave_reduce(d);
    if (lane == 0) {
        const float bsdot = ws[SCAL + ((w < 2) ? w : (w + 2))];
        d1_s[w] = mk*mk*acc + mk*bsdot;
        d3_s[w] = d;
    }
    __syncthreads();

    const int l = tid, m = b*NL + l, o = brs*NL + l;
    out[O_FT_S + o] = d1_s[0] + ws[DXL + 0*1024 + m] + d3_s[0] + ft_bs[0];
    out[O_FT_E + o] = d1_s[1] + ws[DXL + 1*1024 + m] + d3_s[1] + ft_be[0];
    out[O_BH_S + o] = d1_s[2] + ws[DXL + 2*1024 + m] + d3_s[2] + bh_bs[0];
    out[O_BH_E + o] = d1_s[3] + ws[DXL + 3*1024 + m] + d3_s[3] + bh_be[0];
}

extern "C" void kernel_launch(void* const* d_in, const int* in_sizes, int n_in,
                              void* d_out, int out_size, void* d_ws, size_t ws_size,
                              hipStream_t stream) {
    const float* X        = (const float*)d_in[0];
    const float* X_mean   = (const float*)d_in[1];
    const int*   sk       = (const int*)d_in[3];
    const float* sk_mask  = (const float*)d_in[4];
    const float* sem      = (const float*)d_in[5];
    const float* transe   = (const float*)d_in[6];
    const float* fh_ws = (const float*)d_in[7],  *fh_bs = (const float*)d_in[8];
    const float* fh_we = (const float*)d_in[9],  *fh_be = (const float*)d_in[10];
    const float* bt_ws = (const float*)d_in[11], *bt_bs = (const float*)d_in[12];
    const float* bt_we = (const float*)d_in[13], *bt_be = (const float*)d_in[14];
    const float* ft_ws = (const float*)d_in[15], *ft_bs = (const float*)d_in[16];
    const float* ft_we = (const float*)d_in[17], *ft_be = (const float*)d_in[18];
    const float* bh_ws = (const float*)d_in[19], *bh_bs = (const float*)d_in[20];
    const float* bh_we = (const float*)d_in[21], *bh_be = (const float*)d_in[22];
    const float* fra_Wx = (const float*)d_in[23], *fra_bx = (const float*)d_in[24];
    const float* fra_Wr = (const float*)d_in[25], *fra_br = (const float*)d_in[26];
    const float* fra_Wg = (const float*)d_in[27], *fra_bg = (const float*)d_in[28];
    const float* fra_V  = (const float*)d_in[29], *fra_bv = (const float*)d_in[30];
    const float* bra_Wx = (const float*)d_in[31], *bra_bx = (const float*)d_in[32];
    const float* bra_Wr = (const float*)d_in[33], *bra_br = (const float*)d_in[34];
    const float* bra_Wg = (const float*)d_in[35], *bra_bg = (const float*)d_in[36];
    const float* bra_V  = (const float*)d_in[37], *bra_bv = (const float*)d_in[38];
    const float* ffe_Ws = (const float*)d_in[39], *ffe_bs = (const float*)d_in[40];
    const float* ffe_Wx = (const float*)d_in[41], *ffe_bx = (const float*)d_in[42];
    const float* bfe_Ws = (const float*)d_in[43], *bfe_bs = (const float*)d_in[44];
    const float* bfe_Wx = (const float*)d_in[45], *bfe_bx = (const float*)d_in[46];

    float* out = (float*)d_out;
    float* ws  = (float*)d_ws;

    k_setup<<<dim3(992), dim3(512), 0, stream>>>(X, fra_Wx, bra_Wx, sem, transe, X_mean,
        fra_Wr, fra_br, fra_Wg, fra_bg, bra_Wr, bra_br, bra_Wg, bra_bg,
        ffe_Ws, ffe_bs, ffe_Wx, ffe_bx, bfe_Ws, bfe_bs, bfe_Wx, bfe_bx,
        ft_ws, ft_we, bh_ws, bh_we, ws);

    k_wx<<<dim3(512), dim3(256), 0, stream>>>(fra_bx, bra_bx, ws);

    k_attn_dxl<<<dim3(576), dim3(512), 0, stream>>>(X, fra_V, fra_bv, bra_V, bra_bv,
        fh_ws, fh_bs, fh_we, fh_be, bt_ws, bt_bs, bt_we, bt_be, ws, out);

    k_skf<<<dim3(256), dim3(256), 0, stream>>>(X, sk, sk_mask,
        ft_ws, ft_bs, ft_we, ft_be, bh_ws, bh_bs, bh_we, bh_be, ws, out);
}

// Round 4
// 205.063 us; speedup vs baseline: 1.2248x; 1.2248x over previous
//
#include <hip/hip_runtime.h>
#include <hip/hip_bf16.h>

#define NB 4
#define NR 8
#define NS 8
#define NL 256
#define NH 768
#define NA 256
#define NTD 100

// ---- workspace layout (float offsets) ----
#define WX_F 0
#define WX_B (WX_F + NB*NL*NA)      // 262144
#define WR_F (WX_B + NB*NL*NA)      // 524288
#define WR_B (WR_F + NR*NA)
#define WG_F (WR_B + NR*NA)
#define WG_B (WG_F + NB*NA)
#define C_F  (WG_B + NB*NA)         // (B,R,H)
#define C_B  (C_F + NB*NR*NH)
#define QV   (C_B + NB*NR*NH)       // 8 vectors of 768
#define SCAL (QV + 8*NH)            // 8 scalars
#define DXL  (SCAL + 8)             // 4 x (B*L)
#define ATT16 (DXL + 4*NB*NL)       // bf16 a[2*4][16][256]  (rows 8..15 zero) = 16384 float slots
#define XB   (ATT16 + 16384)        // bf16 Xb[1024][768]
#define WT   (XB + (NB*NL*NH)/2)    // bf16 Wt[2][256][768]
#define XT   (WT + (2*NA*NH)/2)     // bf16 XT[4][768][256]

// output offsets (floats)
#define O_FT_S 4096
#define O_FT_E 69632
#define O_BH_S 135168
#define O_BH_E 200704

typedef __attribute__((ext_vector_type(8))) short short8;
typedef __attribute__((ext_vector_type(4))) float f32x4;

struct bh4 { __hip_bfloat16 a, b, c, d; };

__device__ __forceinline__ float tanh_fast(float x) {
    x = fminf(15.f, fmaxf(-15.f, x));
    float t = __expf(2.f * x);
    return (t - 1.f) / (t + 1.f);
}

__device__ __forceinline__ float wave_reduce(float v) {
    #pragma unroll
    for (int off = 32; off > 0; off >>= 1) v += __shfl_down(v, off);
    return v;
}

// ================= K1: setup =================
// bid 0..383    : X f32->bf16 (2048 elems/block)
// bid 384..575  : W transpose+cvt (2 32x32 tiles/block)
// bid 576..959  : X transpose+cvt -> XT bf16 (2 32x32 tiles/block, 768 tiles)
// bid 960..983  : vec@mat (wr/wg rows)
// bid 984..991  : scalar dots
// bid 992..1375 : 768x768 matvec pairs (q/u vectors)
__global__ void __launch_bounds__(512) k_setup(const float* __restrict__ X,
                      const float* __restrict__ fra_Wx, const float* __restrict__ bra_Wx,
                      const float* __restrict__ sem, const float* __restrict__ transe,
                      const float* __restrict__ X_mean,
                      const float* __restrict__ fra_Wr, const float* __restrict__ fra_br,
                      const float* __restrict__ fra_Wg, const float* __restrict__ fra_bg,
                      const float* __restrict__ bra_Wr, const float* __restrict__ bra_br,
                      const float* __restrict__ bra_Wg, const float* __restrict__ bra_bg,
                      const float* __restrict__ ffe_Ws, const float* __restrict__ ffe_bs,
                      const float* __restrict__ ffe_Wx, const float* __restrict__ ffe_bx,
                      const float* __restrict__ bfe_Ws, const float* __restrict__ bfe_bs,
                      const float* __restrict__ bfe_Wx, const float* __restrict__ bfe_bx,
                      const float* __restrict__ ft_ws, const float* __restrict__ ft_we,
                      const float* __restrict__ bh_ws, const float* __restrict__ bh_we,
                      float* __restrict__ ws) {
    __shared__ float smem[2112];
    const int bid = blockIdx.x, tid = threadIdx.x;

    if (bid < 384) {
        __hip_bfloat16* xb = (__hip_bfloat16*)(ws + XB);
        const int i0 = bid*2048 + tid*4;
        const float4 v = *(const float4*)(X + i0);
        bh4 o = { __float2bfloat16(v.x), __float2bfloat16(v.y),
                  __float2bfloat16(v.z), __float2bfloat16(v.w) };
        *(bh4*)(xb + i0) = o;
    } else if (bid < 576) {
        __hip_bfloat16* wt = (__hip_bfloat16*)(ws + WT);
        const int t2 = bid - 384;               // 0..191
        const int mt = t2 / 96;                 // 0 fwd, 1 bwd
        const int half = tid >> 8, tid2 = tid & 255;
        const int tile = (t2 % 96)*2 + half;    // 0..191
        const int h0 = (tile >> 3) * 32, c0 = (tile & 7) * 32;
        const float* W = mt ? bra_Wx : fra_Wx;
        float (*sh)[33] = (float(*)[33])(smem + half*1056);
        const int r = tid2 >> 5, c = tid2 & 31;
        #pragma unroll
        for (int i = 0; i < 4; ++i)
            sh[r + 8*i][c] = W[(size_t)(h0 + r + 8*i)*NA + c0 + c];
        __syncthreads();
        #pragma unroll
        for (int i = 0; i < 4; ++i)
            wt[(size_t)(mt*NA + c0 + r + 8*i)*NH + h0 + c] = __float2bfloat16(sh[c][r + 8*i]);
    } else if (bid < 960) {
        // XT[b][h][l] = X[b][l][h], bf16
        __hip_bfloat16* xt = (__hip_bfloat16*)(ws + XT);
        const int t2 = bid - 576;               // 0..383
        const int half = tid >> 8, tid2 = tid & 255;
        const int tile = t2*2 + half;           // 0..767
        const int b = tile / 192, trem = tile % 192;
        const int h0 = (trem >> 3) * 32, l0 = (trem & 7) * 32;
        float (*sh)[33] = (float(*)[33])(smem + half*1056);
        const int r = tid2 >> 5, c = tid2 & 31;   // r: l-offset rows (8 at a time), c: h-offset
        #pragma unroll
        for (int i = 0; i < 4; ++i)
            sh[r + 8*i][c] = X[(size_t)(b*NL + l0 + r + 8*i)*NH + h0 + c];
        __syncthreads();
        // write: thread (r,c) writes XT[b][h0 + r + 8i][l0 + c] = sh[c][r + 8i]
        #pragma unroll
        for (int i = 0; i < 4; ++i)
            xt[(size_t)(b*NH + h0 + r + 8*i)*NL + l0 + c] = __float2bfloat16(sh[c][r + 8*i]);
    } else if (bid < 984) {
        float* sh = smem;
        float* red2 = smem + 768;
        const int q = bid - 960;
        const float* s; const float* W; const float* bias; float* out; int K;
        if (q < 8)       { s = sem + q*NH;         W = fra_Wr; bias = fra_br; out = ws + WR_F + q*NA;      K = NH;  }
        else if (q < 16) { s = transe + (q-8)*NTD; W = bra_Wr; bias = bra_br; out = ws + WR_B + (q-8)*NA;  K = NTD; }
        else if (q < 20) { s = X_mean + (q-16)*NH; W = fra_Wg; bias = fra_bg; out = ws + WG_F + (q-16)*NA; K = NH;  }
        else             { s = X_mean + (q-20)*NH; W = bra_Wg; bias = bra_bg; out = ws + WG_B + (q-20)*NA; K = NH;  }
        for (int j = tid; j < K; j += 512) sh[j] = s[j];
        __syncthreads();
        const int half = tid >> 8, col = tid & 255;
        const int khalf = (K/2) & ~15;
        const int k0 = half ? khalf : 0, k1 = half ? K : khalf;
        const float* Wc = W + col;
        float acc = 0.f;
        int k = k0;
        for (; k + 16 <= k1; k += 16) {
            float wb[16];
            #pragma unroll
            for (int i = 0; i < 16; ++i) wb[i] = Wc[(size_t)(k+i)*NA];
            #pragma unroll
            for (int i = 0; i < 16; ++i) acc += sh[k+i] * wb[i];
        }
        for (; k < k1; ++k) acc += sh[k] * Wc[(size_t)k*NA];
        red2[half*256 + col] = acc;
        __syncthreads();
        if (half == 0) out[col] = red2[col] + red2[256 + col] + bias[col];
    } else if (bid < 992) {
        float* red2 = smem;
        const int q = bid - 984;
        const float* a; const float* b2;
        switch (q) {
            case 0: a = ffe_bs; b2 = ft_ws; break;
            case 1: a = ffe_bs; b2 = ft_we; break;
            case 2: a = ffe_bx; b2 = ft_ws; break;
            case 3: a = ffe_bx; b2 = ft_we; break;
            case 4: a = bfe_bs; b2 = bh_ws; break;
            case 5: a = bfe_bs; b2 = bh_we; break;
            case 6: a = bfe_bx; b2 = bh_ws; break;
            default: a = bfe_bx; b2 = bh_we; break;
        }
        float p = a[tid]*b2[tid];
        if (tid < 256) p += a[tid+512]*b2[tid+512];
        red2[tid] = p; __syncthreads();
        for (int s2 = 256; s2 > 0; s2 >>= 1) { if (tid < s2) red2[tid] += red2[tid + s2]; __syncthreads(); }
        if (tid == 0) ws[SCAL + q] = red2[0];
    } else {
        const int idx = bid - 992;              // 0..383
        const int mi = idx / 96;
        const int row = (idx % 96)*8 + (tid >> 6);
        const int lane = tid & 63;
        const float* M; const float* v0; const float* v1; bool self;
        switch (mi) {
            case 0: M = ffe_Ws; v0 = ft_ws; v1 = ft_we; self = false; break;
            case 1: M = bfe_Ws; v0 = bh_ws; v1 = bh_we; self = false; break;
            case 2: M = ffe_Wx; v0 = ft_ws; v1 = ft_we; self = true;  break;
            default: M = bfe_Wx; v0 = bh_ws; v1 = bh_we; self = true; break;
        }
        const float4* mr4 = (const float4*)(M + (size_t)row*NH);
        const float4* va4 = (const float4*)v0;
        const float4* vb4 = (const float4*)v1;
        float a0 = 0.f, a1 = 0.f;
        #pragma unroll
        for (int i = 0; i < 3; ++i) {
            const float4 m4 = mr4[lane + 64*i];
            const float4 x4 = va4[lane + 64*i];
            const float4 y4 = vb4[lane + 64*i];
            a0 += m4.x*x4.x + m4.y*x4.y + m4.z*x4.z + m4.w*x4.w;
            a1 += m4.x*y4.x + m4.y*y4.y + m4.z*y4.z + m4.w*y4.w;
        }
        a0 = wave_reduce(a0); a1 = wave_reduce(a1);
        if (lane == 0) {
            ws[QV + (mi*2 + 0)*NH + row] = a0 + (self ? v0[row] : 0.f);
            ws[QV + (mi*2 + 1)*NH + row] = a1 + (self ? v1[row] : 0.f);
        }
    }
}

// ================= K2: bf16 MFMA GEMM  wx = X @ W + b =================
__global__ void __launch_bounds__(256) k_wx(const float* __restrict__ fra_bx,
                                            const float* __restrict__ bra_bx,
                                            float* __restrict__ ws) {
    const __hip_bfloat16* xb = (const __hip_bfloat16*)(ws + XB);
    const __hip_bfloat16* wt = (const __hip_bfloat16*)(ws + WT);
    const int bid = blockIdx.x, tid = threadIdx.x;
    const int fb = bid >> 8;
    const int rt = (bid & 255) >> 2, cg = bid & 3;
    const int wv = tid >> 6, lane = tid & 63;
    const int m0 = rt * 16, c0 = cg * 64 + wv * 16;
    const int r16 = lane & 15, koff = (lane >> 4) * 8;

    const short8* ap = (const short8*)(xb + (size_t)(m0 + r16)*NH + koff);
    const short8* bp = (const short8*)(wt + (size_t)(fb*NA + c0 + r16)*NH + koff);

    f32x4 acc = {0.f, 0.f, 0.f, 0.f};
    #pragma unroll
    for (int ks = 0; ks < 24; ks += 4) {
        short8 a0 = ap[(ks+0)*4], b0 = bp[(ks+0)*4];
        short8 a1 = ap[(ks+1)*4], b1 = bp[(ks+1)*4];
        short8 a2 = ap[(ks+2)*4], b2 = bp[(ks+2)*4];
        short8 a3 = ap[(ks+3)*4], b3 = bp[(ks+3)*4];
        acc = __builtin_amdgcn_mfma_f32_16x16x32_bf16(a0, b0, acc, 0, 0, 0);
        acc = __builtin_amdgcn_mfma_f32_16x16x32_bf16(a1, b1, acc, 0, 0, 0);
        acc = __builtin_amdgcn_mfma_f32_16x16x32_bf16(a2, b2, acc, 0, 0, 0);
        acc = __builtin_amdgcn_mfma_f32_16x16x32_bf16(a3, b3, acc, 0, 0, 0);
    }
    const float* bia = fb ? bra_bx : fra_bx;
    float* outp = ws + (fb ? WX_B : WX_F);
    const int col = c0 + r16;
    const float bb = bia[col];
    const int rbase = m0 + (lane >> 4) * 4;
    #pragma unroll
    for (int j = 0; j < 4; ++j)
        outp[(size_t)(rbase + j)*NA + col] = acc[j] + bb;
}

// ================= K3: attn e -> softmax -> a (bf16, zero-padded tile) =================
__global__ void __launch_bounds__(512) k_attn(const float* __restrict__ fra_V, const float* __restrict__ fra_bv,
                       const float* __restrict__ bra_V, const float* __restrict__ bra_bv,
                       float* __restrict__ ws) {
    __shared__ float wa_s[NA], v_s[NA], red[NL], part[NL];
    const int bid = blockIdx.x, tid = threadIdx.x;
    const int fb = bid >> 5, b = (bid >> 3) & 3, r = bid & 7;
    const int l = tid & 255, half = tid >> 8;

    const float* wr = ws + (fb ? WR_B : WR_F) + r*NA;
    const float* wg = ws + (fb ? WG_B : WG_F) + b*NA;
    const float* V  = fb ? bra_V : fra_V;
    const float  bv = fb ? bra_bv[0] : fra_bv[0];
    const float* wxp = ws + (fb ? WX_B : WX_F);

    if (tid < 256) { wa_s[tid] = wr[tid] + wg[tid]; v_s[tid] = V[tid]; }
    __syncthreads();

    const float4* wxrow = (const float4*)(wxp + (size_t)(b*NL + l)*NA + half*128);
    float acc = 0.f;
    for (int a0 = 0; a0 < 32; a0 += 8) {
        float4 wb[8];
        #pragma unroll
        for (int i = 0; i < 8; ++i) wb[i] = wxrow[a0 + i];
        #pragma unroll
        for (int i = 0; i < 8; ++i) {
            const int a = half*128 + (a0 + i)*4;
            acc += tanh_fast(wb[i].x + wa_s[a+0]) * v_s[a+0];
            acc += tanh_fast(wb[i].y + wa_s[a+1]) * v_s[a+1];
            acc += tanh_fast(wb[i].z + wa_s[a+2]) * v_s[a+2];
            acc += tanh_fast(wb[i].w + wa_s[a+3]) * v_s[a+3];
        }
    }
    if (half) part[l] = acc;
    __syncthreads();

    float e = 0.f;
    if (!half) e = acc + part[l] + bv;
    if (tid < 256) red[tid] = e;
    __syncthreads();
    for (int s2 = 128; s2 > 0; s2 >>= 1) { if (tid < s2) red[tid] = fmaxf(red[tid], red[tid+s2]); __syncthreads(); }
    const float mx = red[0];
    __syncthreads();
    float p = 0.f;
    if (tid < 256) { p = __expf(e - mx); red[tid] = p; }
    __syncthreads();
    for (int s2 = 128; s2 > 0; s2 >>= 1) { if (tid < s2) red[tid] += red[tid+s2]; __syncthreads(); }
    if (tid < 256) {
        __hip_bfloat16* att = (__hip_bfloat16*)(ws + ATT16);
        const int g = fb*NB + b;
        att[(size_t)(g*16 + r)*NL + tid]     = __float2bfloat16(p / red[0]);
        att[(size_t)(g*16 + 8 + r)*NL + tid] = __float2bfloat16(0.f);
    }
}

// ================= K4: ctx via MFMA — c[r,h] = sum_l a[r,l] X[b,l,h] =================
// grid 96: bid -> g = bid/12 (fb*4+b), hc = bid%12. wave computes 16x16 tile over K=256.
__global__ void __launch_bounds__(256) k_ctx(float* __restrict__ ws) {
    const __hip_bfloat16* att = (const __hip_bfloat16*)(ws + ATT16);
    const __hip_bfloat16* xt  = (const __hip_bfloat16*)(ws + XT);
    const int bid = blockIdx.x, tid = threadIdx.x;
    const int g = bid / 12, hc = bid % 12;
    const int fb = g >> 2, b = g & 3;
    const int wv = tid >> 6, lane = tid & 63;
    const int h0 = hc*64 + wv*16;
    const int r16 = lane & 15, khi = lane >> 4;

    const short8* ap = (const short8*)(att + (size_t)(g*16 + r16)*NL) + khi;
    const short8* bp = (const short8*)(xt + (size_t)(b*NH + h0 + r16)*NL) + khi;

    f32x4 acc = {0.f, 0.f, 0.f, 0.f};
    #pragma unroll
    for (int ks = 0; ks < 8; ++ks) {
        short8 af = ap[ks*4];
        short8 bf = bp[ks*4];
        acc = __builtin_amdgcn_mfma_f32_16x16x32_bf16(af, bf, acc, 0, 0, 0);
    }
    float* cc = ws + (fb ? C_B : C_F) + (size_t)b*NR*NH;
    const int col = h0 + r16;
    const int rbase = khi * 4;
    #pragma unroll
    for (int j = 0; j < 4; ++j) {
        const int r = rbase + j;
        if (r < 8) cc[(size_t)r*NH + col] = acc[j];
    }
}

// ================= K5: dxl — per (b,l): fh/bt heads to out, X·u dots to ws =================
__global__ void __launch_bounds__(256) k_dxl(const float* __restrict__ X,
                      const float* __restrict__ fh_ws, const float* __restrict__ fh_bs,
                      const float* __restrict__ fh_we, const float* __restrict__ fh_be,
                      const float* __restrict__ bt_ws, const float* __restrict__ bt_bs,
                      const float* __restrict__ bt_we, const float* __restrict__ bt_be,
                      float* __restrict__ ws, float* __restrict__ out) {
    __shared__ float xr[NH];
    const int m = blockIdx.x;
    const int tid = threadIdx.x, w = tid >> 6, lane = tid & 63;

    if (tid < 192) ((float4*)xr)[tid] = ((const float4*)(X + (size_t)m*NH))[tid];
    __syncthreads();

    const float* v0; const float* v1; float add0, add1; float* o0; float* o1;
    if (w == 0)      { v0 = fh_ws; add0 = fh_bs[0]; o0 = out;        v1 = fh_we; add1 = fh_be[0]; o1 = out + 1024; }
    else if (w == 1) { v0 = bt_ws; add0 = bt_bs[0]; o0 = out + 2048; v1 = bt_we; add1 = bt_be[0]; o1 = out + 3072; }
    else if (w == 2) { v0 = ws + QV + 4*NH; add0 = ws[SCAL+2]; o0 = ws + DXL;
                       v1 = ws + QV + 5*NH; add1 = ws[SCAL+3]; o1 = ws + DXL + 1024; }
    else             { v0 = ws + QV + 6*NH; add0 = ws[SCAL+6]; o0 = ws + DXL + 2048;
                       v1 = ws + QV + 7*NH; add1 = ws[SCAL+7]; o1 = ws + DXL + 3072; }

    const float4* xr4 = (const float4*)xr;
    const float4* v04 = (const float4*)v0;
    const float4* v14 = (const float4*)v1;
    float a0 = 0.f, a1 = 0.f;
    #pragma unroll
    for (int i = 0; i < 3; ++i) {
        const float4 x4 = xr4[lane + 64*i];
        const float4 p4 = v04[lane + 64*i];
        const float4 q4 = v14[lane + 64*i];
        a0 += x4.x*p4.x + x4.y*p4.y + x4.z*p4.z + x4.w*p4.w;
        a1 += x4.x*q4.x + x4.y*q4.y + x4.z*q4.z + x4.w*q4.w;
    }
    a0 = wave_reduce(a0); a1 = wave_reduce(a1);
    if (lane == 0) { o0[m] = a0 + add0; o1[m] = a1 + add1; }
}

// ================= K6: span gather + q-dots + d3 + final output =================
__global__ void __launch_bounds__(256) k_skf(const float* __restrict__ X, const int* __restrict__ sk,
                     const float* __restrict__ sk_mask,
                     const float* __restrict__ ft_ws, const float* __restrict__ ft_bs,
                     const float* __restrict__ ft_we, const float* __restrict__ ft_be,
                     const float* __restrict__ bh_ws, const float* __restrict__ bh_bs,
                     const float* __restrict__ bh_we, const float* __restrict__ bh_be,
                     const float* __restrict__ ws, float* __restrict__ out) {
    __shared__ float avg[NH];
    __shared__ float d1_s[4], d3_s[4];
    const int brs = blockIdx.x;
    const int tid = threadIdx.x, w = tid >> 6, lane = tid & 63;
    const int b = brs >> 6, br = brs >> 3;
    const int i0 = sk[brs*2], i1 = sk[brs*2 + 1];
    const float mk = sk_mask[brs];

    if (tid < 192) {
        const float4 x0 = ((const float4*)(X + (size_t)(b*NL + i0)*NH))[tid];
        const float4 x1 = ((const float4*)(X + (size_t)(b*NL + i1)*NH))[tid];
        float4 o; o.x = 0.5f*(x0.x+x1.x); o.y = 0.5f*(x0.y+x1.y);
        o.z = 0.5f*(x0.z+x1.z); o.w = 0.5f*(x0.w+x1.w);
        ((float4*)avg)[tid] = o;
    }
    __syncthreads();

    const float4* q4 = (const float4*)(ws + QV + w*NH);
    const float4* av4 = (const float4*)avg;
    const float4* c4 = (const float4*)(ws + ((w < 2) ? C_F : C_B) + (size_t)br*NH);
    const float* v = (w == 0) ? ft_ws : (w == 1) ? ft_we : (w == 2) ? bh_ws : bh_we;
    const float4* vv4 = (const float4*)v;
    float acc = 0.f, d = 0.f;
    #pragma unroll
    for (int i = 0; i < 3; ++i) {
        const float4 a4 = av4[lane + 64*i];
        const float4 b4 = q4[lane + 64*i];
        const float4 e4 = c4[lane + 64*i];
        const float4 f4 = vv4[lane + 64*i];
        acc += a4.x*b4.x + a4.y*b4.y + a4.z*b4.z + a4.w*b4.w;
        d   += e4.x*f4.x + e4.y*f4.y + e4.z*f4.z + e4.w*f4.w;
    }
    acc = wave_reduce(acc); d = wave_reduce(d);
    if (lane == 0) {
        const float bsdot = ws[SCAL + ((w < 2) ? w : (w + 2))];
        d1_s[w] = mk*mk*acc + mk*bsdot;
        d3_s[w] = d;
    }
    __syncthreads();

    const int l = tid, m = b*NL + l, o = brs*NL + l;
    out[O_FT_S + o] = d1_s[0] + ws[DXL + 0*1024 + m] + d3_s[0] + ft_bs[0];
    out[O_FT_E + o] = d1_s[1] + ws[DXL + 1*1024 + m] + d3_s[1] + ft_be[0];
    out[O_BH_S + o] = d1_s[2] + ws[DXL + 2*1024 + m] + d3_s[2] + bh_bs[0];
    out[O_BH_E + o] = d1_s[3] + ws[DXL + 3*1024 + m] + d3_s[3] + bh_be[0];
}

extern "C" void kernel_launch(void* const* d_in, const int* in_sizes, int n_in,
                              void* d_out, int out_size, void* d_ws, size_t ws_size,
                              hipStream_t stream) {
    const float* X        = (const float*)d_in[0];
    const float* X_mean   = (const float*)d_in[1];
    const int*   sk       = (const int*)d_in[3];
    const float* sk_mask  = (const float*)d_in[4];
    const float* sem      = (const float*)d_in[5];
    const float* transe   = (const float*)d_in[6];
    const float* fh_ws = (const float*)d_in[7],  *fh_bs = (const float*)d_in[8];
    const float* fh_we = (const float*)d_in[9],  *fh_be = (const float*)d_in[10];
    const float* bt_ws = (const float*)d_in[11], *bt_bs = (const float*)d_in[12];
    const float* bt_we = (const float*)d_in[13], *bt_be = (const float*)d_in[14];
    const float* ft_ws = (const float*)d_in[15], *ft_bs = (const float*)d_in[16];
    const float* ft_we = (const float*)d_in[17], *ft_be = (const float*)d_in[18];
    const float* bh_ws = (const float*)d_in[19], *bh_bs = (const float*)d_in[20];
    const float* bh_we = (const float*)d_in[21], *bh_be = (const float*)d_in[22];
    const float* fra_Wx = (const float*)d_in[23], *fra_bx = (const float*)d_in[24];
    const float* fra_Wr = (const float*)d_in[25], *fra_br = (const float*)d_in[26];
    const float* fra_Wg = (const float*)d_in[27], *fra_bg = (const float*)d_in[28];
    const float* fra_V  = (const float*)d_in[29], *fra_bv = (const float*)d_in[30];
    const float* bra_Wx = (const float*)d_in[31], *bra_bx = (const float*)d_in[32];
    const float* bra_Wr = (const float*)d_in[33], *bra_br = (const float*)d_in[34];
    const float* bra_Wg = (const float*)d_in[35], *bra_bg = (const float*)d_in[36];
    const float* bra_V  = (const float*)d_in[37], *bra_bv = (const float*)d_in[38];
    const float* ffe_Ws = (const float*)d_in[39], *ffe_bs = (const float*)d_in[40];
    const float* ffe_Wx = (const float*)d_in[41], *ffe_bx = (const float*)d_in[42];
    const float* bfe_Ws = (const float*)d_in[43], *bfe_bs = (const float*)d_in[44];
    const float* bfe_Wx = (const float*)d_in[45], *bfe_bx = (const float*)d_in[46];

    float* out = (float*)d_out;
    float* ws  = (float*)d_ws;

    k_setup<<<dim3(1376), dim3(512), 0, stream>>>(X, fra_Wx, bra_Wx, sem, transe, X_mean,
        fra_Wr, fra_br, fra_Wg, fra_bg, bra_Wr, bra_br, bra_Wg, bra_bg,
        ffe_Ws, ffe_bs, ffe_Wx, ffe_bx, bfe_Ws, bfe_bs, bfe_Wx, bfe_bx,
        ft_ws, ft_we, bh_ws, bh_we, ws);

    k_wx<<<dim3(512), dim3(256), 0, stream>>>(fra_bx, bra_bx, ws);

    k_attn<<<dim3(64), dim3(512), 0, stream>>>(fra_V, fra_bv, bra_V, bra_bv, ws);

    k_ctx<<<dim3(96), dim3(256), 0, stream>>>(ws);

    k_dxl<<<dim3(1024), dim3(256), 0, stream>>>(X, fh_ws, fh_bs, fh_we, fh_be,
        bt_ws, bt_bs, bt_we, bt_be, ws, out);

    k_skf<<<dim3(256), dim3(256), 0, stream>>>(X, sk, sk_mask,
        ft_ws, ft_bs, ft_we, ft_be, bh_ws, bh_bs, bh_we, bh_be, ws, out);
}

// Round 5
// 202.956 us; speedup vs baseline: 1.2375x; 1.0104x over previous
//
#include <hip/hip_runtime.h>
#include <hip/hip_bf16.h>

#define NB 4
#define NR 8
#define NS 8
#define NL 256
#define NH 768
#define NA 256
#define NTD 100

// ---- workspace layout (float offsets) ----
#define WX_F 0
#define WX_B (WX_F + NB*NL*NA)      // 262144
#define WR_F (WX_B + NB*NL*NA)      // 524288
#define WR_B (WR_F + NR*NA)
#define WG_F (WR_B + NR*NA)
#define WG_B (WG_F + NB*NA)
#define C_F  (WG_B + NB*NA)         // (B,R,H)
#define C_B  (C_F + NB*NR*NH)
#define QV   (C_B + NB*NR*NH)       // 8 vectors of 768
#define SCAL (QV + 8*NH)            // 8 scalars
#define DXL  (SCAL + 8)             // 4 x (B*L)
#define ATT16 (DXL + 4*NB*NL)       // bf16 a[2*4][16][256]  (rows 8..15 zero)
#define XB   (ATT16 + 16384)        // bf16 Xb[1024][768]
#define WT   (XB + (NB*NL*NH)/2)    // bf16 Wt[2][256][768]
#define XT   (WT + (2*NA*NH)/2)     // bf16 XT[4][768][256]

// output offsets (floats)
#define O_FT_S 4096
#define O_FT_E 69632
#define O_BH_S 135168
#define O_BH_E 200704

typedef __attribute__((ext_vector_type(8))) short short8;
typedef __attribute__((ext_vector_type(4))) float f32x4;

__device__ __forceinline__ float tanh_fast(float x) {
    x = fminf(15.f, fmaxf(-15.f, x));
    float t = __expf(2.f * x);
    return (t - 1.f) / (t + 1.f);
}

__device__ __forceinline__ float wave_reduce(float v) {
    #pragma unroll
    for (int off = 32; off > 0; off >>= 1) v += __shfl_down(v, off);
    return v;
}

// ================= K1: setup =================
// bid 0..191   : W transpose+cvt (2 32x32 tiles/block)
// bid 192..575 : X -> XB (bf16 row-major) AND XT (bf16 transposed), single read of X
// bid 576..599 : vec@mat (wr/wg rows)
// bid 600..607 : scalar dots
// bid 608..991 : 768x768 matvec pairs (q/u vectors)
__global__ void __launch_bounds__(512) k_setup(const float* __restrict__ X,
                      const float* __restrict__ fra_Wx, const float* __restrict__ bra_Wx,
                      const float* __restrict__ sem, const float* __restrict__ transe,
                      const float* __restrict__ X_mean,
                      const float* __restrict__ fra_Wr, const float* __restrict__ fra_br,
                      const float* __restrict__ fra_Wg, const float* __restrict__ fra_bg,
                      const float* __restrict__ bra_Wr, const float* __restrict__ bra_br,
                      const float* __restrict__ bra_Wg, const float* __restrict__ bra_bg,
                      const float* __restrict__ ffe_Ws, const float* __restrict__ ffe_bs,
                      const float* __restrict__ ffe_Wx, const float* __restrict__ ffe_bx,
                      const float* __restrict__ bfe_Ws, const float* __restrict__ bfe_bs,
                      const float* __restrict__ bfe_Wx, const float* __restrict__ bfe_bx,
                      const float* __restrict__ ft_ws, const float* __restrict__ ft_we,
                      const float* __restrict__ bh_ws, const float* __restrict__ bh_we,
                      float* __restrict__ ws) {
    __shared__ float smem[2112];
    const int bid = blockIdx.x, tid = threadIdx.x;

    if (bid < 192) {
        __hip_bfloat16* wt = (__hip_bfloat16*)(ws + WT);
        const int mt = bid / 96;                // 0 fwd, 1 bwd
        const int half = tid >> 8, tid2 = tid & 255;
        const int tile = (bid % 96)*2 + half;   // 0..191
        const int h0 = (tile >> 3) * 32, c0 = (tile & 7) * 32;
        const float* W = mt ? bra_Wx : fra_Wx;
        float (*sh)[33] = (float(*)[33])(smem + half*1056);
        const int r = tid2 >> 5, c = tid2 & 31;
        #pragma unroll
        for (int i = 0; i < 4; ++i)
            sh[r + 8*i][c] = W[(size_t)(h0 + r + 8*i)*NA + c0 + c];
        __syncthreads();
        #pragma unroll
        for (int i = 0; i < 4; ++i)
            wt[(size_t)(mt*NA + c0 + r + 8*i)*NH + h0 + c] = __float2bfloat16(sh[c][r + 8*i]);
    } else if (bid < 576) {
        // XB[b][l][h] (row-major bf16) + XT[b][h][l] (transposed bf16), one X read
        __hip_bfloat16* xb = (__hip_bfloat16*)(ws + XB);
        __hip_bfloat16* xt = (__hip_bfloat16*)(ws + XT);
        const int t2 = bid - 192;               // 0..383
        const int half = tid >> 8, tid2 = tid & 255;
        const int tile = t2*2 + half;           // 0..767
        const int b = tile / 192, trem = tile % 192;
        const int h0 = (trem >> 3) * 32, l0 = (trem & 7) * 32;
        float (*sh)[33] = (float(*)[33])(smem + half*1056);
        const int r = tid2 >> 5, c = tid2 & 31;
        #pragma unroll
        for (int i = 0; i < 4; ++i) {
            const float v = X[(size_t)(b*NL + l0 + r + 8*i)*NH + h0 + c];
            sh[r + 8*i][c] = v;
            xb[(size_t)(b*NL + l0 + r + 8*i)*NH + h0 + c] = __float2bfloat16(v);
        }
        __syncthreads();
        #pragma unroll
        for (int i = 0; i < 4; ++i)
            xt[(size_t)(b*NH + h0 + r + 8*i)*NL + l0 + c] = __float2bfloat16(sh[c][r + 8*i]);
    } else if (bid < 600) {
        float* sh = smem;
        float* red2 = smem + 768;
        const int q = bid - 576;
        const float* s; const float* W; const float* bias; float* out; int K;
        if (q < 8)       { s = sem + q*NH;         W = fra_Wr; bias = fra_br; out = ws + WR_F + q*NA;      K = NH;  }
        else if (q < 16) { s = transe + (q-8)*NTD; W = bra_Wr; bias = bra_br; out = ws + WR_B + (q-8)*NA;  K = NTD; }
        else if (q < 20) { s = X_mean + (q-16)*NH; W = fra_Wg; bias = fra_bg; out = ws + WG_F + (q-16)*NA; K = NH;  }
        else             { s = X_mean + (q-20)*NH; W = bra_Wg; bias = bra_bg; out = ws + WG_B + (q-20)*NA; K = NH;  }
        for (int j = tid; j < K; j += 512) sh[j] = s[j];
        __syncthreads();
        const int half = tid >> 8, col = tid & 255;
        const int khalf = (K/2) & ~15;
        const int k0 = half ? khalf : 0, k1 = half ? K : khalf;
        const float* Wc = W + col;
        float acc = 0.f;
        int k = k0;
        for (; k + 16 <= k1; k += 16) {
            float wb[16];
            #pragma unroll
            for (int i = 0; i < 16; ++i) wb[i] = Wc[(size_t)(k+i)*NA];
            #pragma unroll
            for (int i = 0; i < 16; ++i) acc += sh[k+i] * wb[i];
        }
        for (; k < k1; ++k) acc += sh[k] * Wc[(size_t)k*NA];
        red2[half*256 + col] = acc;
        __syncthreads();
        if (half == 0) out[col] = red2[col] + red2[256 + col] + bias[col];
    } else if (bid < 608) {
        float* red2 = smem;
        const int q = bid - 600;
        const float* a; const float* b2;
        switch (q) {
            case 0: a = ffe_bs; b2 = ft_ws; break;
            case 1: a = ffe_bs; b2 = ft_we; break;
            case 2: a = ffe_bx; b2 = ft_ws; break;
            case 3: a = ffe_bx; b2 = ft_we; break;
            case 4: a = bfe_bs; b2 = bh_ws; break;
            case 5: a = bfe_bs; b2 = bh_we; break;
            case 6: a = bfe_bx; b2 = bh_ws; break;
            default: a = bfe_bx; b2 = bh_we; break;
        }
        float p = a[tid]*b2[tid];
        if (tid < 256) p += a[tid+512]*b2[tid+512];
        red2[tid] = p; __syncthreads();
        for (int s2 = 256; s2 > 0; s2 >>= 1) { if (tid < s2) red2[tid] += red2[tid + s2]; __syncthreads(); }
        if (tid == 0) ws[SCAL + q] = red2[0];
    } else {
        const int idx = bid - 608;              // 0..383
        const int mi = idx / 96;
        const int row = (idx % 96)*8 + (tid >> 6);
        const int lane = tid & 63;
        const float* M; const float* v0; const float* v1; bool self;
        switch (mi) {
            case 0: M = ffe_Ws; v0 = ft_ws; v1 = ft_we; self = false; break;
            case 1: M = bfe_Ws; v0 = bh_ws; v1 = bh_we; self = false; break;
            case 2: M = ffe_Wx; v0 = ft_ws; v1 = ft_we; self = true;  break;
            default: M = bfe_Wx; v0 = bh_ws; v1 = bh_we; self = true; break;
        }
        const float4* mr4 = (const float4*)(M + (size_t)row*NH);
        const float4* va4 = (const float4*)v0;
        const float4* vb4 = (const float4*)v1;
        float a0 = 0.f, a1 = 0.f;
        #pragma unroll
        for (int i = 0; i < 3; ++i) {
            const float4 m4 = mr4[lane + 64*i];
            const float4 x4 = va4[lane + 64*i];
            const float4 y4 = vb4[lane + 64*i];
            a0 += m4.x*x4.x + m4.y*x4.y + m4.z*x4.z + m4.w*x4.w;
            a1 += m4.x*y4.x + m4.y*y4.y + m4.z*y4.z + m4.w*y4.w;
        }
        a0 = wave_reduce(a0); a1 = wave_reduce(a1);
        if (lane == 0) {
            ws[QV + (mi*2 + 0)*NH + row] = a0 + (self ? v0[row] : 0.f);
            ws[QV + (mi*2 + 1)*NH + row] = a1 + (self ? v1[row] : 0.f);
        }
    }
}

// ================= K2: bf16 MFMA GEMM (wx = X@W+b) + dxl blocks =================
// bid 0..511    : wx MFMA tiles (proven k_wx code)
// bid 512..1535 : per (b,l) head dots (proven k_dxl code)
__global__ void __launch_bounds__(256) k_wx_dxl(const float* __restrict__ fra_bx,
                      const float* __restrict__ bra_bx,
                      const float* __restrict__ X,
                      const float* __restrict__ fh_ws, const float* __restrict__ fh_bs,
                      const float* __restrict__ fh_we, const float* __restrict__ fh_be,
                      const float* __restrict__ bt_ws, const float* __restrict__ bt_bs,
                      const float* __restrict__ bt_we, const float* __restrict__ bt_be,
                      float* __restrict__ ws, float* __restrict__ out) {
    __shared__ float xr[NH];
    const int tid = threadIdx.x;

    if (blockIdx.x < 512) {
        const __hip_bfloat16* xb = (const __hip_bfloat16*)(ws + XB);
        const __hip_bfloat16* wt = (const __hip_bfloat16*)(ws + WT);
        const int bid = blockIdx.x;
        const int fb = bid >> 8;
        const int rt = (bid & 255) >> 2, cg = bid & 3;
        const int wv = tid >> 6, lane = tid & 63;
        const int m0 = rt * 16, c0 = cg * 64 + wv * 16;
        const int r16 = lane & 15, koff = (lane >> 4) * 8;

        const short8* ap = (const short8*)(xb + (size_t)(m0 + r16)*NH + koff);
        const short8* bp = (const short8*)(wt + (size_t)(fb*NA + c0 + r16)*NH + koff);

        f32x4 acc = {0.f, 0.f, 0.f, 0.f};
        #pragma unroll
        for (int ks = 0; ks < 24; ks += 4) {
            short8 a0 = ap[(ks+0)*4], b0 = bp[(ks+0)*4];
            short8 a1 = ap[(ks+1)*4], b1 = bp[(ks+1)*4];
            short8 a2 = ap[(ks+2)*4], b2 = bp[(ks+2)*4];
            short8 a3 = ap[(ks+3)*4], b3 = bp[(ks+3)*4];
            acc = __builtin_amdgcn_mfma_f32_16x16x32_bf16(a0, b0, acc, 0, 0, 0);
            acc = __builtin_amdgcn_mfma_f32_16x16x32_bf16(a1, b1, acc, 0, 0, 0);
            acc = __builtin_amdgcn_mfma_f32_16x16x32_bf16(a2, b2, acc, 0, 0, 0);
            acc = __builtin_amdgcn_mfma_f32_16x16x32_bf16(a3, b3, acc, 0, 0, 0);
        }
        const float* bia = fb ? bra_bx : fra_bx;
        float* outp = ws + (fb ? WX_B : WX_F);
        const int col = c0 + r16;
        const float bb = bia[col];
        const int rbase = m0 + (lane >> 4) * 4;
        #pragma unroll
        for (int j = 0; j < 4; ++j)
            outp[(size_t)(rbase + j)*NA + col] = acc[j] + bb;
    } else {
        const int m = blockIdx.x - 512;
        const int w = tid >> 6, lane = tid & 63;

        if (tid < 192) ((float4*)xr)[tid] = ((const float4*)(X + (size_t)m*NH))[tid];
        __syncthreads();

        const float* v0; const float* v1; float add0, add1; float* o0; float* o1;
        if (w == 0)      { v0 = fh_ws; add0 = fh_bs[0]; o0 = out;        v1 = fh_we; add1 = fh_be[0]; o1 = out + 1024; }
        else if (w == 1) { v0 = bt_ws; add0 = bt_bs[0]; o0 = out + 2048; v1 = bt_we; add1 = bt_be[0]; o1 = out + 3072; }
        else if (w == 2) { v0 = ws + QV + 4*NH; add0 = ws[SCAL+2]; o0 = ws + DXL;
                           v1 = ws + QV + 5*NH; add1 = ws[SCAL+3]; o1 = ws + DXL + 1024; }
        else             { v0 = ws + QV + 6*NH; add0 = ws[SCAL+6]; o0 = ws + DXL + 2048;
                           v1 = ws + QV + 7*NH; add1 = ws[SCAL+7]; o1 = ws + DXL + 3072; }

        const float4* xr4 = (const float4*)xr;
        const float4* v04 = (const float4*)v0;
        const float4* v14 = (const float4*)v1;
        float a0 = 0.f, a1 = 0.f;
        #pragma unroll
        for (int i = 0; i < 3; ++i) {
            const float4 x4 = xr4[lane + 64*i];
            const float4 p4 = v04[lane + 64*i];
            const float4 q4 = v14[lane + 64*i];
            a0 += x4.x*p4.x + x4.y*p4.y + x4.z*p4.z + x4.w*p4.w;
            a1 += x4.x*q4.x + x4.y*q4.y + x4.z*q4.z + x4.w*q4.w;
        }
        a0 = wave_reduce(a0); a1 = wave_reduce(a1);
        if (lane == 0) { o0[m] = a0 + add0; o1[m] = a1 + add1; }
    }
}

// ================= K3: attn e -> softmax -> a (bf16, zero-padded tile) =================
__global__ void __launch_bounds__(512) k_attn(const float* __restrict__ fra_V, const float* __restrict__ fra_bv,
                       const float* __restrict__ bra_V, const float* __restrict__ bra_bv,
                       float* __restrict__ ws) {
    __shared__ float wa_s[NA], v_s[NA], red[NL], part[NL];
    const int bid = blockIdx.x, tid = threadIdx.x;
    const int fb = bid >> 5, b = (bid >> 3) & 3, r = bid & 7;
    const int l = tid & 255, half = tid >> 8;

    const float* wr = ws + (fb ? WR_B : WR_F) + r*NA;
    const float* wg = ws + (fb ? WG_B : WG_F) + b*NA;
    const float* V  = fb ? bra_V : fra_V;
    const float  bv = fb ? bra_bv[0] : fra_bv[0];
    const float* wxp = ws + (fb ? WX_B : WX_F);

    if (tid < 256) { wa_s[tid] = wr[tid] + wg[tid]; v_s[tid] = V[tid]; }
    __syncthreads();

    const float4* wxrow = (const float4*)(wxp + (size_t)(b*NL + l)*NA + half*128);
    float acc = 0.f;
    for (int a0 = 0; a0 < 32; a0 += 8) {
        float4 wb[8];
        #pragma unroll
        for (int i = 0; i < 8; ++i) wb[i] = wxrow[a0 + i];
        #pragma unroll
        for (int i = 0; i < 8; ++i) {
            const int a = half*128 + (a0 + i)*4;
            acc += tanh_fast(wb[i].x + wa_s[a+0]) * v_s[a+0];
            acc += tanh_fast(wb[i].y + wa_s[a+1]) * v_s[a+1];
            acc += tanh_fast(wb[i].z + wa_s[a+2]) * v_s[a+2];
            acc += tanh_fast(wb[i].w + wa_s[a+3]) * v_s[a+3];
        }
    }
    if (half) part[l] = acc;
    __syncthreads();

    float e = 0.f;
    if (!half) e = acc + part[l] + bv;
    if (tid < 256) red[tid] = e;
    __syncthreads();
    for (int s2 = 128; s2 > 0; s2 >>= 1) { if (tid < s2) red[tid] = fmaxf(red[tid], red[tid+s2]); __syncthreads(); }
    const float mx = red[0];
    __syncthreads();
    float p = 0.f;
    if (tid < 256) { p = __expf(e - mx); red[tid] = p; }
    __syncthreads();
    for (int s2 = 128; s2 > 0; s2 >>= 1) { if (tid < s2) red[tid] += red[tid+s2]; __syncthreads(); }
    if (tid < 256) {
        __hip_bfloat16* att = (__hip_bfloat16*)(ws + ATT16);
        const int g = fb*NB + b;
        att[(size_t)(g*16 + r)*NL + tid]     = __float2bfloat16(p / red[0]);
        att[(size_t)(g*16 + 8 + r)*NL + tid] = __float2bfloat16(0.f);
    }
}

// ================= K4: ctx via MFMA — c[r,h] = sum_l a[r,l] X[b,l,h] =================
__global__ void __launch_bounds__(256) k_ctx(float* __restrict__ ws) {
    const __hip_bfloat16* att = (const __hip_bfloat16*)(ws + ATT16);
    const __hip_bfloat16* xt  = (const __hip_bfloat16*)(ws + XT);
    const int bid = blockIdx.x, tid = threadIdx.x;
    const int g = bid / 12, hc = bid % 12;
    const int fb = g >> 2, b = g & 3;
    const int wv = tid >> 6, lane = tid & 63;
    const int h0 = hc*64 + wv*16;
    const int r16 = lane & 15, khi = lane >> 4;

    const short8* ap = (const short8*)(att + (size_t)(g*16 + r16)*NL) + khi;
    const short8* bp = (const short8*)(xt + (size_t)(b*NH + h0 + r16)*NL) + khi;

    f32x4 acc = {0.f, 0.f, 0.f, 0.f};
    #pragma unroll
    for (int ks = 0; ks < 8; ++ks) {
        short8 af = ap[ks*4];
        short8 bf = bp[ks*4];
        acc = __builtin_amdgcn_mfma_f32_16x16x32_bf16(af, bf, acc, 0, 0, 0);
    }
    float* cc = ws + (fb ? C_B : C_F) + (size_t)b*NR*NH;
    const int col = h0 + r16;
    const int rbase = khi * 4;
    #pragma unroll
    for (int j = 0; j < 4; ++j) {
        const int r = rbase + j;
        if (r < 8) cc[(size_t)r*NH + col] = acc[j];
    }
}

// ================= K5: span gather + q-dots + d3 + final output =================
__global__ void __launch_bounds__(256) k_skf(const float* __restrict__ X, const int* __restrict__ sk,
                     const float* __restrict__ sk_mask,
                     const float* __restrict__ ft_ws, const float* __restrict__ ft_bs,
                     const float* __restrict__ ft_we, const float* __restrict__ ft_be,
                     const float* __restrict__ bh_ws, const float* __restrict__ bh_bs,
                     const float* __restrict__ bh_we, const float* __restrict__ bh_be,
                     const float* __restrict__ ws, float* __restrict__ out) {
    __shared__ float avg[NH];
    __shared__ float d1_s[4], d3_s[4];
    const int brs = blockIdx.x;
    const int tid = threadIdx.x, w = tid >> 6, lane = tid & 63;
    const int b = brs >> 6, br = brs >> 3;
    const int i0 = sk[brs*2], i1 = sk[brs*2 + 1];
    const float mk = sk_mask[brs];

    if (tid < 192) {
        const float4 x0 = ((const float4*)(X + (size_t)(b*NL + i0)*NH))[tid];
        const float4 x1 = ((const float4*)(X + (size_t)(b*NL + i1)*NH))[tid];
        float4 o; o.x = 0.5f*(x0.x+x1.x); o.y = 0.5f*(x0.y+x1.y);
        o.z = 0.5f*(x0.z+x1.z); o.w = 0.5f*(x0.w+x1.w);
        ((float4*)avg)[tid] = o;
    }
    __syncthreads();

    const float4* q4 = (const float4*)(ws + QV + w*NH);
    const float4* av4 = (const float4*)avg;
    const float4* c4 = (const float4*)(ws + ((w < 2) ? C_F : C_B) + (size_t)br*NH);
    const float* v = (w == 0) ? ft_ws : (w == 1) ? ft_we : (w == 2) ? bh_ws : bh_we;
    const float4* vv4 = (const float4*)v;
    float acc = 0.f, d = 0.f;
    #pragma unroll
    for (int i = 0; i < 3; ++i) {
        const float4 a4 = av4[lane + 64*i];
        const float4 b4 = q4[lane + 64*i];
        const float4 e4 = c4[lane + 64*i];
        const float4 f4 = vv4[lane + 64*i];
        acc += a4.x*b4.x + a4.y*b4.y + a4.z*b4.z + a4.w*b4.w;
        d   += e4.x*f4.x + e4.y*f4.y + e4.z*f4.z + e4.w*f4.w;
    }
    acc = wave_reduce(acc); d = wave_reduce(d);
    if (lane == 0) {
        const float bsdot = ws[SCAL + ((w < 2) ? w : (w + 2))];
        d1_s[w] = mk*mk*acc + mk*bsdot;
        d3_s[w] = d;
    }
    __syncthreads();

    const int l = tid, m = b*NL + l, o = brs*NL + l;
    out[O_FT_S + o] = d1_s[0] + ws[DXL + 0*1024 + m] + d3_s[0] + ft_bs[0];
    out[O_FT_E + o] = d1_s[1] + ws[DXL + 1*1024 + m] + d3_s[1] + ft_be[0];
    out[O_BH_S + o] = d1_s[2] + ws[DXL + 2*1024 + m] + d3_s[2] + bh_bs[0];
    out[O_BH_E + o] = d1_s[3] + ws[DXL + 3*1024 + m] + d3_s[3] + bh_be[0];
}

extern "C" void kernel_launch(void* const* d_in, const int* in_sizes, int n_in,
                              void* d_out, int out_size, void* d_ws, size_t ws_size,
                              hipStream_t stream) {
    const float* X        = (const float*)d_in[0];
    const float* X_mean   = (const float*)d_in[1];
    const int*   sk       = (const int*)d_in[3];
    const float* sk_mask  = (const float*)d_in[4];
    const float* sem      = (const float*)d_in[5];
    const float* transe   = (const float*)d_in[6];
    const float* fh_ws = (const float*)d_in[7],  *fh_bs = (const float*)d_in[8];
    const float* fh_we = (const float*)d_in[9],  *fh_be = (const float*)d_in[10];
    const float* bt_ws = (const float*)d_in[11], *bt_bs = (const float*)d_in[12];
    const float* bt_we = (const float*)d_in[13], *bt_be = (const float*)d_in[14];
    const float* ft_ws = (const float*)d_in[15], *ft_bs = (const float*)d_in[16];
    const float* ft_we = (const float*)d_in[17], *ft_be = (const float*)d_in[18];
    const float* bh_ws = (const float*)d_in[19], *bh_bs = (const float*)d_in[20];
    const float* bh_we = (const float*)d_in[21], *bh_be = (const float*)d_in[22];
    const float* fra_Wx = (const float*)d_in[23], *fra_bx = (const float*)d_in[24];
    const float* fra_Wr = (const float*)d_in[25], *fra_br = (const float*)d_in[26];
    const float* fra_Wg = (const float*)d_in[27], *fra_bg = (const float*)d_in[28];
    const float* fra_V  = (const float*)d_in[29], *fra_bv = (const float*)d_in[30];
    const float* bra_Wx = (const float*)d_in[31], *bra_bx = (const float*)d_in[32];
    const float* bra_Wr = (const float*)d_in[33], *bra_br = (const float*)d_in[34];
    const float* bra_Wg = (const float*)d_in[35], *bra_bg = (const float*)d_in[36];
    const float* bra_V  = (const float*)d_in[37], *bra_bv = (const float*)d_in[38];
    const float* ffe_Ws = (const float*)d_in[39], *ffe_bs = (const float*)d_in[40];
    const float* ffe_Wx = (const float*)d_in[41], *ffe_bx = (const float*)d_in[42];
    const float* bfe_Ws = (const float*)d_in[43], *bfe_bs = (const float*)d_in[44];
    const float* bfe_Wx = (const float*)d_in[45], *bfe_bx = (const float*)d_in[46];

    float* out = (float*)d_out;
    float* ws  = (float*)d_ws;

    k_setup<<<dim3(992), dim3(512), 0, stream>>>(X, fra_Wx, bra_Wx, sem, transe, X_mean,
        fra_Wr, fra_br, fra_Wg, fra_bg, bra_Wr, bra_br, bra_Wg, bra_bg,
        ffe_Ws, ffe_bs, ffe_Wx, ffe_bx, bfe_Ws, bfe_bs, bfe_Wx, bfe_bx,
        ft_ws, ft_we, bh_ws, bh_we, ws);

    k_wx_dxl<<<dim3(1536), dim3(256), 0, stream>>>(fra_bx, bra_bx, X,
        fh_ws, fh_bs, fh_we, fh_be, bt_ws, bt_bs, bt_we, bt_be, ws, out);

    k_attn<<<dim3(64), dim3(512), 0, stream>>>(fra_V, fra_bv, bra_V, bra_bv, ws);

    k_ctx<<<dim3(96), dim3(256), 0, stream>>>(ws);

    k_skf<<<dim3(256), dim3(256), 0, stream>>>(X, sk, sk_mask,
        ft_ws, ft_bs, ft_we, ft_be, bh_ws, bh_bs, bh_we, bh_be, ws, out);
}